// Round 1
// baseline (15910.176 us; speedup 1.0000x reference)
//
#include <hip/hip_runtime.h>
#include <hip/hip_bf16.h>
#include <cstdint>
#include <cstddef>

// FFJORD: B=8192, D=128, H=1024, 2 bijectors x 32 RK4 steps x 4 stages.
// Strategy round 0: bf16 MFMA GEMMs (m97-structure 128^2 tile), fused epilogues:
//   L1: H1 = tanh(Xb @ W1[:128] + b1 + t*W1[128])
//   L2: H2 = tanh(H1 @ W2 + b2)
//   L3: k  = H2 @ W3 + b3, fused RK4 stage update (kacc, next input bf16, x update)

#define BSZ 8192
#define DD  128
#define HH  1024

typedef __attribute__((ext_vector_type(8))) __bf16 bf16x8;
typedef __attribute__((ext_vector_type(4))) float  fx4;

__device__ __forceinline__ float fast_tanh(float x) {
  float xc = fminf(fmaxf(x, -9.0f), 9.0f);
  float u = __expf(2.0f * xc);           // v_exp_f32 path
  return (u - 1.0f) * __builtin_amdgcn_rcpf(u + 1.0f);
}

// ---------------- prep: copy x, bf16-cast x, transpose+cast weights ----------
__global__ void prep_kernel(const float* __restrict__ in0,
                            const float* __restrict__ W1,
                            const float* __restrict__ W2,
                            const float* __restrict__ W3,
                            float* __restrict__ xcur,
                            __hip_bfloat16* __restrict__ inbuf,
                            __hip_bfloat16* __restrict__ W1t,
                            __hip_bfloat16* __restrict__ W2t,
                            __hip_bfloat16* __restrict__ W3t) {
  size_t i = (size_t)blockIdx.x * blockDim.x + threadIdx.x;
  const size_t R0 = (size_t)BSZ * DD;       // 1048576
  const size_t R1 = 2u * 128 * 1024;        // 262144
  const size_t R2 = 2u * 1024 * 1024;       // 2097152
  const size_t R3 = 2u * 1024 * 128;        // 262144
  if (i < R0) {
    float v = in0[i];
    xcur[i] = v;
    inbuf[i] = __float2bfloat16(v);
    return;
  }
  i -= R0;
  if (i < R1) {  // W1t[bij][n][k] = W1[bij][k][n], k<128,n<1024
    size_t bij = i >> 17, rem = i & 131071;
    size_t n = rem >> 7, k = rem & 127;
    W1t[(bij << 17) + rem] = __float2bfloat16(W1[bij * (129 * 1024) + k * 1024 + n]);
    return;
  }
  i -= R1;
  if (i < R2) {  // W2t[bij][n][k] = W2[bij][k][n]
    size_t bij = i >> 20, rem = i & 1048575;
    size_t n = rem >> 10, k = rem & 1023;
    W2t[(bij << 20) + rem] = __float2bfloat16(W2[(bij << 20) + k * 1024 + n]);
    return;
  }
  i -= R2;
  if (i < R3) {  // W3t[bij][n][k] = W3[bij][k][n], n<128,k<1024
    size_t bij = i >> 17, rem = i & 131071;
    size_t n = rem >> 10, k = rem & 1023;
    W3t[(bij << 17) + rem] = __float2bfloat16(W3[(bij << 17) + k * 128 + n]);
  }
}

// ---------------- fused GEMM -------------------------------------------------
// A: MxK row-major bf16.  Bt: NxK row-major bf16 (pre-transposed weights).
// MODE 0: Hout = tanh(A@B + bias + tval*tw)   (tw may be null)
// MODE 1: kv = A@B + bias; RK4 stage update on (xin, kacc, xout, nextin), tval = dt
template <int BM, int BN, int WR, int WC, int MODE>
__global__ void __launch_bounds__(256)
gemm_fused(const __hip_bfloat16* __restrict__ A,
           const __hip_bfloat16* __restrict__ Bt,
           int M, int N, int K,
           const float* __restrict__ bias,
           const float* __restrict__ tw,
           float tval,
           __hip_bfloat16* __restrict__ Hout,
           int stage,
           const float* __restrict__ xin,
           float* __restrict__ kacc,
           float* __restrict__ xout,
           __hip_bfloat16* __restrict__ nextin) {
  constexpr int BK = 32;
  constexpr int WTM = BM / WR;
  constexpr int WTN = BN / WC;
  constexpr int MR = WTM / 16;
  constexpr int NR = WTN / 16;
  __shared__ __align__(16) short Asm[BM * BK];
  __shared__ __align__(16) short Bsm[BN * BK];

  const int tid = threadIdx.x;
  const int lane = tid & 63;
  const int w = tid >> 6;
  const int wr = w / WC;
  const int wc = w % WC;
  const int m0 = blockIdx.x * BM;
  const int n0 = blockIdx.y * BN;
  const int l16 = lane & 15;
  const int lk8 = (lane >> 4) * 8;  // k-element offset of this lane's frag chunk

  fx4 acc[MR][NR];
#pragma unroll
  for (int i = 0; i < MR; ++i)
#pragma unroll
    for (int j = 0; j < NR; ++j) acc[i][j] = fx4{0.f, 0.f, 0.f, 0.f};

  const char* Ag = (const char*)(A + (size_t)m0 * K);
  const char* Bg = (const char*)(Bt + (size_t)n0 * K);

  for (int k0 = 0; k0 < K; k0 += BK) {
    __syncthreads();  // previous iter's frag reads done before overwrite
    constexpr int IA = (BM * BK * 2) / (256 * 16);
#pragma unroll
    for (int q = 0; q < IA; ++q) {
      int off = q * 4096 + tid * 16;     // byte offset in tile (row-major BMx32)
      int row = off >> 6;                // 64B per LDS row
      int kb = off & 63;                 // byte within row
      const void* src = Ag + (size_t)row * ((size_t)K * 2) + (size_t)k0 * 2 + kb;
      __builtin_amdgcn_global_load_lds(
          (const __attribute__((address_space(1))) void*)src,
          (__attribute__((address_space(3))) void*)((char*)Asm + off), 16, 0, 0);
    }
    constexpr int IB = (BN * BK * 2) / (256 * 16);
#pragma unroll
    for (int q = 0; q < IB; ++q) {
      int off = q * 4096 + tid * 16;
      int row = off >> 6;
      int kb = off & 63;
      const void* src = Bg + (size_t)row * ((size_t)K * 2) + (size_t)k0 * 2 + kb;
      __builtin_amdgcn_global_load_lds(
          (const __attribute__((address_space(1))) void*)src,
          (__attribute__((address_space(3))) void*)((char*)Bsm + off), 16, 0, 0);
    }
    __syncthreads();  // drains vmcnt (compiler emits waitcnt before s_barrier)

    bf16x8 af[MR], bfr[NR];
#pragma unroll
    for (int i = 0; i < MR; ++i) {
      int row = wr * WTM + i * 16 + l16;
      af[i] = *(const bf16x8*)(Asm + row * BK + lk8);
    }
#pragma unroll
    for (int j = 0; j < NR; ++j) {
      int rowb = wc * WTN + j * 16 + l16;
      bfr[j] = *(const bf16x8*)(Bsm + rowb * BK + lk8);
    }
#pragma unroll
    for (int i = 0; i < MR; ++i)
#pragma unroll
      for (int j = 0; j < NR; ++j)
        acc[i][j] = __builtin_amdgcn_mfma_f32_16x16x32_bf16(af[i], bfr[j],
                                                            acc[i][j], 0, 0, 0);
  }

  // Epilogue. C/D layout (verified m89/m91): col = lane&15, row = (lane>>4)*4 + r
  const int r0 = (lane >> 4) * 4;
#pragma unroll
  for (int i = 0; i < MR; ++i) {
    const int growb = m0 + wr * WTM + i * 16 + r0;
#pragma unroll
    for (int j = 0; j < NR; ++j) {
      const int gcol = n0 + wc * WTN + j * 16 + l16;
      const float bj = bias[gcol];
      float twj = 0.f;
      if (MODE == 0) twj = (tw != nullptr) ? tw[gcol] : 0.f;
#pragma unroll
      for (int r = 0; r < 4; ++r) {
        const int grow = growb + r;
        const float v = acc[i][j][r];
        if (MODE == 0) {
          float c = v + bj + tval * twj;
          Hout[(size_t)grow * N + gcol] = __float2bfloat16(fast_tanh(c));
        } else {
          const float kv = v + bj;
          const size_t idx = (size_t)grow * N + gcol;
          const float x = xin[idx];
          float xs;
          if (stage == 0)      { kacc[idx] = kv;           xs = x + 0.5f * tval * kv; }
          else if (stage == 1) { kacc[idx] += 2.f * kv;    xs = x + 0.5f * tval * kv; }
          else if (stage == 2) { kacc[idx] += 2.f * kv;    xs = x + tval * kv; }
          else { float xn = x + (tval / 6.f) * (kacc[idx] + kv);
                 xout[idx] = xn;                           xs = xn; }
          nextin[idx] = __float2bfloat16(xs);
        }
      }
    }
  }
}

// ---------------- host -------------------------------------------------------
extern "C" void kernel_launch(void* const* d_in, const int* in_sizes, int n_in,
                              void* d_out, int out_size, void* d_ws, size_t ws_size,
                              hipStream_t stream) {
  const float* inputs = (const float*)d_in[0];
  const float* W1 = (const float*)d_in[1];
  const float* b1 = (const float*)d_in[2];
  const float* W2 = (const float*)d_in[3];
  const float* b2 = (const float*)d_in[4];
  const float* W3 = (const float*)d_in[5];
  const float* b3 = (const float*)d_in[6];
  float* out = (float*)d_out;

  char* ws = (char*)d_ws;
  float* xcur = (float*)ws;                                      // 4 MB
  float* kacc = (float*)(ws + (4u << 20));                       // 4 MB
  __hip_bfloat16* inbuf = (__hip_bfloat16*)(ws + (8u << 20));    // 2 MB
  __hip_bfloat16* H1b = (__hip_bfloat16*)(ws + (10u << 20));     // 16 MB
  __hip_bfloat16* H2b = (__hip_bfloat16*)(ws + (26u << 20));     // 16 MB
  __hip_bfloat16* W1t = (__hip_bfloat16*)(ws + (42u << 20));     // 512 KB
  __hip_bfloat16* W2t = (__hip_bfloat16*)(ws + (42u << 20) + (512u << 10)); // 4 MB
  __hip_bfloat16* W3t = (__hip_bfloat16*)(ws + (46u << 20) + (512u << 10)); // 512 KB

  {
    const size_t total = (size_t)BSZ * DD + 2u * 128 * 1024 + 2u * 1024 * 1024 + 2u * 1024 * 128;
    const int blocks = (int)((total + 255) / 256);
    prep_kernel<<<blocks, 256, 0, stream>>>(inputs, W1, W2, W3, xcur, inbuf, W1t, W2t, W3t);
  }

  const float dt = 1.0f / 32.0f;
  for (int bij = 0; bij < 2; ++bij) {
    const __hip_bfloat16* w1t_b = W1t + (size_t)bij * 128 * 1024;
    const __hip_bfloat16* w2t_b = W2t + (size_t)bij * 1024 * 1024;
    const __hip_bfloat16* w3t_b = W3t + (size_t)bij * 1024 * 128;
    const float* b1_b = b1 + (size_t)bij * 1024;
    const float* b2_b = b2 + (size_t)bij * 1024;
    const float* b3_b = b3 + (size_t)bij * 128;
    const float* tw = W1 + (size_t)bij * (129 * 1024) + 128 * 1024;  // time row (fp32)

    for (int step = 0; step < 32; ++step) {
      for (int s = 0; s < 4; ++s) {
        const float t = step * dt + (s == 0 ? 0.f : (s == 3 ? dt : 0.5f * dt));
        // L1: H1 = tanh(inbuf @ W1 + b1 + t*w1t)   M=8192 N=1024 K=128
        gemm_fused<128, 128, 2, 2, 0><<<dim3(64, 8), 256, 0, stream>>>(
            inbuf, w1t_b, BSZ, HH, DD, b1_b, tw, t, H1b,
            0, nullptr, nullptr, nullptr, nullptr);
        // L2: H2 = tanh(H1 @ W2 + b2)              M=8192 N=1024 K=1024
        gemm_fused<128, 128, 2, 2, 0><<<dim3(64, 8), 256, 0, stream>>>(
            H1b, w2t_b, BSZ, HH, HH, b2_b, nullptr, 0.f, H2b,
            0, nullptr, nullptr, nullptr, nullptr);
        // L3 + RK4: k = H2 @ W3 + b3               M=8192 N=128 K=1024
        const bool last = (bij == 1 && step == 31 && s == 3);
        gemm_fused<64, 64, 2, 2, 1><<<dim3(128, 2), 256, 0, stream>>>(
            H2b, w3t_b, BSZ, DD, HH, b3_b, nullptr, dt, nullptr,
            s, xcur, kacc, last ? out : xcur, inbuf);
      }
    }
  }
}

// Round 3
// 12113.274 us; speedup vs baseline: 1.3134x; 1.3134x over previous
//
#include <hip/hip_runtime.h>
#include <hip/hip_bf16.h>
#include <cstdint>
#include <cstddef>

// FFJORD: B=8192, D=128, H=1024, 2 bijectors x 32 RK4 steps x 4 stages.
// Round 2: same as round 1 (L1 single-stage big-tile, L2/L3 BK=64 + T2 swizzle,
// coalesced RK4 epilogue via LDS bounce, XCD grid map); fixed bf16 bit access.

#define BSZ 8192
#define DD  128
#define HH  1024

typedef __attribute__((ext_vector_type(8))) __bf16 bf16x8;
typedef __attribute__((ext_vector_type(4))) float  fx4;
typedef __attribute__((ext_vector_type(4))) unsigned short us4;

__device__ __forceinline__ unsigned short bf16bits(float x) {
  return __builtin_bit_cast(unsigned short, __float2bfloat16(x));
}

__device__ __forceinline__ float fast_tanh(float x) {
  float xc = fminf(fmaxf(x, -9.0f), 9.0f);
  float u = __expf(2.0f * xc);
  return (u - 1.0f) * __builtin_amdgcn_rcpf(u + 1.0f);
}

__device__ __forceinline__ void gll16(const void* g, void* l) {
  __builtin_amdgcn_global_load_lds((const __attribute__((address_space(1))) void*)g,
                                   (__attribute__((address_space(3))) void*)l, 16, 0, 0);
}

// ---------------- prep: copy x, bf16-cast x, transpose+cast weights ----------
__global__ void prep_kernel(const float* __restrict__ in0,
                            const float* __restrict__ W1,
                            const float* __restrict__ W2,
                            const float* __restrict__ W3,
                            float* __restrict__ xcur,
                            __hip_bfloat16* __restrict__ inbuf,
                            __hip_bfloat16* __restrict__ W1t,
                            __hip_bfloat16* __restrict__ W2t,
                            __hip_bfloat16* __restrict__ W3t) {
  size_t i = (size_t)blockIdx.x * blockDim.x + threadIdx.x;
  const size_t R0 = (size_t)BSZ * DD;
  const size_t R1 = 2u * 128 * 1024;
  const size_t R2 = 2u * 1024 * 1024;
  const size_t R3 = 2u * 1024 * 128;
  if (i < R0) {
    float v = in0[i];
    xcur[i] = v;
    inbuf[i] = __float2bfloat16(v);
    return;
  }
  i -= R0;
  if (i < R1) {  // W1t[bij][n][k] = W1[bij][k][n], k<128,n<1024
    size_t bij = i >> 17, rem = i & 131071;
    size_t n = rem >> 7, k = rem & 127;
    W1t[(bij << 17) + rem] = __float2bfloat16(W1[bij * (129 * 1024) + k * 1024 + n]);
    return;
  }
  i -= R1;
  if (i < R2) {  // W2t[bij][n][k] = W2[bij][k][n]
    size_t bij = i >> 20, rem = i & 1048575;
    size_t n = rem >> 10, k = rem & 1023;
    W2t[(bij << 20) + rem] = __float2bfloat16(W2[(bij << 20) + k * 1024 + n]);
    return;
  }
  i -= R2;
  if (i < R3) {  // W3t[bij][n][k] = W3[bij][k][n], n<128,k<1024
    size_t bij = i >> 17, rem = i & 131071;
    size_t n = rem >> 10, k = rem & 1023;
    W3t[(bij << 17) + rem] = __float2bfloat16(W3[(bij << 17) + k * 128 + n]);
  }
}

// ---------------- L1: H1 = tanh(X @ W1 + b1 + t*tw), K=128 single-stage ------
// X [8192][128] bf16, W1t [1024][128] bf16. Tile 128x128, grid 512 (1D, XCD-mapped).
__global__ void __launch_bounds__(256)
l1_kernel(const __hip_bfloat16* __restrict__ X,
          const __hip_bfloat16* __restrict__ W1t,
          const float* __restrict__ b1,
          const float* __restrict__ tw,
          float tval,
          __hip_bfloat16* __restrict__ H1) {
  __shared__ char lds[65536];  // A 32K | B 32K (B area reused for output bounce)
  const int tid = threadIdx.x;
  const int lane = tid & 63;
  const int w = tid >> 6;
  const int wr = w >> 1, wc = w & 1;
  const int bid = blockIdx.x;
  const int xcd = bid & 7, j = bid >> 3;
  const int m_blk = xcd * 8 + (j & 7);   // 0..63
  const int n_blk = j >> 3;              // 0..7
  const int m0 = m_blk * 128, n0 = n_blk * 128;

  const char* Ag = (const char*)(X + (size_t)m0 * 128);    // contiguous 32KB
  const char* Bg = (const char*)(W1t + (size_t)n0 * 128);  // contiguous 32KB
#pragma unroll
  for (int q = 0; q < 8; ++q) {
    int off = q * 4096 + tid * 16;
    int soff = off ^ (((off >> 8) & 7) << 4);  // pre-swizzled source (involution)
    gll16(Ag + soff, lds + off);
    gll16(Bg + soff, lds + 32768 + off);
  }
  __syncthreads();

  const int l16 = lane & 15, lk8 = (lane >> 4) * 8;
  fx4 acc[4][4];
#pragma unroll
  for (int i = 0; i < 4; ++i)
#pragma unroll
    for (int jj = 0; jj < 4; ++jj) acc[i][jj] = fx4{0.f, 0.f, 0.f, 0.f};

#pragma unroll
  for (int kk = 0; kk < 4; ++kk) {
    const int cb = kk * 64 + lk8 * 2;
    bf16x8 af[4], bfr[4];
#pragma unroll
    for (int i = 0; i < 4; ++i) {
      int row = wr * 64 + i * 16 + l16;
      af[i] = *(const bf16x8*)(lds + row * 256 + (cb ^ ((row & 7) << 4)));
    }
#pragma unroll
    for (int jj = 0; jj < 4; ++jj) {
      int rowb = wc * 64 + jj * 16 + l16;
      bfr[jj] = *(const bf16x8*)(lds + 32768 + rowb * 256 + (cb ^ ((rowb & 7) << 4)));
    }
#pragma unroll
    for (int i = 0; i < 4; ++i)
#pragma unroll
      for (int jj = 0; jj < 4; ++jj)
        acc[i][jj] = __builtin_amdgcn_mfma_f32_16x16x32_bf16(af[i], bfr[jj],
                                                             acc[i][jj], 0, 0, 0);
  }

  __syncthreads();  // all frag reads done before overwriting B area
  __hip_bfloat16* Ot = (__hip_bfloat16*)(lds + 32768);  // [128][128]
  const int r0 = (lane >> 4) * 4;
#pragma unroll
  for (int i = 0; i < 4; ++i) {
#pragma unroll
    for (int jj = 0; jj < 4; ++jj) {
      const int col = wc * 64 + jj * 16 + l16;
      const int gcol = n0 + col;
      const float bj = b1[gcol] + tval * tw[gcol];
#pragma unroll
      for (int r = 0; r < 4; ++r) {
        const int row = wr * 64 + i * 16 + r0 + r;
        Ot[row * 128 + col] = __float2bfloat16(fast_tanh(acc[i][jj][r] + bj));
      }
    }
  }
  __syncthreads();
#pragma unroll
  for (int q = 0; q < 8; ++q) {
    int off = (tid + q * 256) * 16;
    int row = off >> 8, cb = off & 255;
    *(float4*)((char*)H1 + (size_t)(m0 + row) * (HH * 2) + n0 * 2 + cb) =
        *(const float4*)(lds + 32768 + off);
  }
}

// ---------------- L2: H2 = tanh(H1 @ W2 + b2), K=1024, BK=64 -----------------
__global__ void __launch_bounds__(256)
l2_kernel(const __hip_bfloat16* __restrict__ A,
          const __hip_bfloat16* __restrict__ Bt,
          const float* __restrict__ bias,
          __hip_bfloat16* __restrict__ H2) {
  __shared__ char lds[32768];  // A tile [128][64] 16K | B tile [128][64] 16K
  const int tid = threadIdx.x;
  const int lane = tid & 63;
  const int w = tid >> 6;
  const int wr = w >> 1, wc = w & 1;
  const int bid = blockIdx.x;
  const int xcd = bid & 7, j = bid >> 3;
  const int m_blk = xcd * 8 + (j & 7);   // 0..63
  const int n_blk = j >> 3;              // 0..7
  const int m0 = m_blk * 128, n0 = n_blk * 128;

  const char* Ag = (const char*)(A + (size_t)m0 * HH);
  const char* Bg = (const char*)(Bt + (size_t)n0 * HH);
  const int l16 = lane & 15, lk8 = (lane >> 4) * 8;

  fx4 acc[4][4];
#pragma unroll
  for (int i = 0; i < 4; ++i)
#pragma unroll
    for (int jj = 0; jj < 4; ++jj) acc[i][jj] = fx4{0.f, 0.f, 0.f, 0.f};

  for (int k0 = 0; k0 < HH; k0 += 64) {
    __syncthreads();
#pragma unroll
    for (int q = 0; q < 4; ++q) {
      int off = q * 4096 + tid * 16;
      int row = off >> 7, cb = off & 127;
      int cbs = cb ^ ((row & 7) << 4);  // swizzled source column
      gll16(Ag + (size_t)row * (HH * 2) + k0 * 2 + cbs, lds + off);
      gll16(Bg + (size_t)row * (HH * 2) + k0 * 2 + cbs, lds + 16384 + off);
    }
    __syncthreads();
#pragma unroll
    for (int kk = 0; kk < 2; ++kk) {
      const int cb = kk * 64 + lk8 * 2;
      bf16x8 af[4], bfr[4];
#pragma unroll
      for (int i = 0; i < 4; ++i) {
        int row = wr * 64 + i * 16 + l16;
        af[i] = *(const bf16x8*)(lds + row * 128 + (cb ^ ((row & 7) << 4)));
      }
#pragma unroll
      for (int jj = 0; jj < 4; ++jj) {
        int rowb = wc * 64 + jj * 16 + l16;
        bfr[jj] = *(const bf16x8*)(lds + 16384 + rowb * 128 + (cb ^ ((rowb & 7) << 4)));
      }
#pragma unroll
      for (int i = 0; i < 4; ++i)
#pragma unroll
        for (int jj = 0; jj < 4; ++jj)
          acc[i][jj] = __builtin_amdgcn_mfma_f32_16x16x32_bf16(af[i], bfr[jj],
                                                               acc[i][jj], 0, 0, 0);
    }
  }

  __syncthreads();
  __hip_bfloat16* Ot = (__hip_bfloat16*)lds;  // [128][128]
  const int r0 = (lane >> 4) * 4;
#pragma unroll
  for (int i = 0; i < 4; ++i) {
#pragma unroll
    for (int jj = 0; jj < 4; ++jj) {
      const int col = wc * 64 + jj * 16 + l16;
      const float bj = bias[n0 + col];
#pragma unroll
      for (int r = 0; r < 4; ++r) {
        const int row = wr * 64 + i * 16 + r0 + r;
        Ot[row * 128 + col] = __float2bfloat16(fast_tanh(acc[i][jj][r] + bj));
      }
    }
  }
  __syncthreads();
#pragma unroll
  for (int q = 0; q < 8; ++q) {
    int off = (tid + q * 256) * 16;
    int row = off >> 8, cb = off & 255;
    *(float4*)((char*)H2 + (size_t)(m0 + row) * (HH * 2) + n0 * 2 + cb) =
        *(const float4*)(lds + off);
  }
}

// ---------------- L3 + RK4: kv = H2 @ W3 + b3; stage update ------------------
// Tile 64x64, grid 256 (1D XCD-mapped), BK=64, coalesced float4 epilogue.
__global__ void __launch_bounds__(256)
l3_kernel(const __hip_bfloat16* __restrict__ A,
          const __hip_bfloat16* __restrict__ Bt,
          const float* __restrict__ b3,
          float dt, int stage,
          const float* __restrict__ xin,
          float* __restrict__ kacc,
          float* __restrict__ xout,
          __hip_bfloat16* __restrict__ nextin) {
  __shared__ char lds[17408];  // staging 16K; epilogue kvs [64][65] f32 = 16640
  const int tid = threadIdx.x;
  const int lane = tid & 63;
  const int w = tid >> 6;
  const int wr = w >> 1, wc = w & 1;
  const int bid = blockIdx.x;
  const int xcd = bid & 7, jj0 = bid >> 3;   // 0..31
  const int m_blk = xcd * 16 + (jj0 & 15);   // 0..127
  const int n_blk = jj0 >> 4;                // 0..1
  const int m0 = m_blk * 64, n0 = n_blk * 64;

  const char* Ag = (const char*)(A + (size_t)m0 * HH);
  const char* Bg = (const char*)(Bt + (size_t)n0 * HH);
  const int l16 = lane & 15, lk8 = (lane >> 4) * 8;

  fx4 acc[2][2];
#pragma unroll
  for (int i = 0; i < 2; ++i)
#pragma unroll
    for (int jj = 0; jj < 2; ++jj) acc[i][jj] = fx4{0.f, 0.f, 0.f, 0.f};

  for (int k0 = 0; k0 < HH; k0 += 64) {
    __syncthreads();
#pragma unroll
    for (int q = 0; q < 2; ++q) {
      int off = q * 4096 + tid * 16;
      int row = off >> 7, cb = off & 127;
      int cbs = cb ^ ((row & 7) << 4);
      gll16(Ag + (size_t)row * (HH * 2) + k0 * 2 + cbs, lds + off);
      gll16(Bg + (size_t)row * (HH * 2) + k0 * 2 + cbs, lds + 8192 + off);
    }
    __syncthreads();
#pragma unroll
    for (int kk = 0; kk < 2; ++kk) {
      const int cb = kk * 64 + lk8 * 2;
      bf16x8 af[2], bfr[2];
#pragma unroll
      for (int i = 0; i < 2; ++i) {
        int row = wr * 32 + i * 16 + l16;
        af[i] = *(const bf16x8*)(lds + row * 128 + (cb ^ ((row & 7) << 4)));
      }
#pragma unroll
      for (int jj = 0; jj < 2; ++jj) {
        int rowb = wc * 32 + jj * 16 + l16;
        bfr[jj] = *(const bf16x8*)(lds + 8192 + rowb * 128 + (cb ^ ((rowb & 7) << 4)));
      }
#pragma unroll
      for (int i = 0; i < 2; ++i)
#pragma unroll
        for (int jj = 0; jj < 2; ++jj)
          acc[i][jj] = __builtin_amdgcn_mfma_f32_16x16x32_bf16(af[i], bfr[jj],
                                                               acc[i][jj], 0, 0, 0);
    }
  }

  __syncthreads();
  float* kvs = (float*)lds;  // [64][65] padded
  const int r0 = (lane >> 4) * 4;
#pragma unroll
  for (int i = 0; i < 2; ++i) {
#pragma unroll
    for (int jj = 0; jj < 2; ++jj) {
      const int col = wc * 32 + jj * 16 + l16;
      const float bj = b3[n0 + col];
#pragma unroll
      for (int r = 0; r < 4; ++r) {
        const int row = wr * 32 + i * 16 + r0 + r;
        kvs[row * 65 + col] = acc[i][jj][r] + bj;
      }
    }
  }
  __syncthreads();

  // RK4 update, fully coalesced: 64 rows x 16 float4 = 1024 float4 / 256 thr
#pragma unroll
  for (int q = 0; q < 4; ++q) {
    const int idx = tid + q * 256;
    const int row = idx >> 4, c4 = idx & 15;
    const size_t gi = (size_t)(m0 + row) * DD + n0 + c4 * 4;
    const float* kp = kvs + row * 65 + c4 * 4;
    float kv0 = kp[0], kv1 = kp[1], kv2 = kp[2], kv3 = kp[3];
    const float4 x = *(const float4*)(xin + gi);
    float4 ka;
    float xs0, xs1, xs2, xs3;
    if (stage == 0) {
      ka = float4{kv0, kv1, kv2, kv3};
      *(float4*)(kacc + gi) = ka;
      xs0 = x.x + 0.5f * dt * kv0; xs1 = x.y + 0.5f * dt * kv1;
      xs2 = x.z + 0.5f * dt * kv2; xs3 = x.w + 0.5f * dt * kv3;
    } else if (stage == 1) {
      ka = *(const float4*)(kacc + gi);
      ka.x += 2.f * kv0; ka.y += 2.f * kv1; ka.z += 2.f * kv2; ka.w += 2.f * kv3;
      *(float4*)(kacc + gi) = ka;
      xs0 = x.x + 0.5f * dt * kv0; xs1 = x.y + 0.5f * dt * kv1;
      xs2 = x.z + 0.5f * dt * kv2; xs3 = x.w + 0.5f * dt * kv3;
    } else if (stage == 2) {
      ka = *(const float4*)(kacc + gi);
      ka.x += 2.f * kv0; ka.y += 2.f * kv1; ka.z += 2.f * kv2; ka.w += 2.f * kv3;
      *(float4*)(kacc + gi) = ka;
      xs0 = x.x + dt * kv0; xs1 = x.y + dt * kv1;
      xs2 = x.z + dt * kv2; xs3 = x.w + dt * kv3;
    } else {
      ka = *(const float4*)(kacc + gi);
      xs0 = x.x + (dt / 6.f) * (ka.x + kv0);
      xs1 = x.y + (dt / 6.f) * (ka.y + kv1);
      xs2 = x.z + (dt / 6.f) * (ka.z + kv2);
      xs3 = x.w + (dt / 6.f) * (ka.w + kv3);
      *(float4*)(xout + gi) = float4{xs0, xs1, xs2, xs3};
    }
    us4 nv;
    nv.x = bf16bits(xs0); nv.y = bf16bits(xs1);
    nv.z = bf16bits(xs2); nv.w = bf16bits(xs3);
    *(us4*)(nextin + gi) = nv;
  }
}

// ---------------- host -------------------------------------------------------
extern "C" void kernel_launch(void* const* d_in, const int* in_sizes, int n_in,
                              void* d_out, int out_size, void* d_ws, size_t ws_size,
                              hipStream_t stream) {
  const float* inputs = (const float*)d_in[0];
  const float* W1 = (const float*)d_in[1];
  const float* b1 = (const float*)d_in[2];
  const float* W2 = (const float*)d_in[3];
  const float* b2 = (const float*)d_in[4];
  const float* W3 = (const float*)d_in[5];
  const float* b3 = (const float*)d_in[6];
  float* out = (float*)d_out;

  char* ws = (char*)d_ws;
  float* xcur = (float*)ws;                                      // 4 MB
  float* kacc = (float*)(ws + (4u << 20));                       // 4 MB
  __hip_bfloat16* inbuf = (__hip_bfloat16*)(ws + (8u << 20));    // 2 MB
  __hip_bfloat16* H1b = (__hip_bfloat16*)(ws + (10u << 20));     // 16 MB
  __hip_bfloat16* H2b = (__hip_bfloat16*)(ws + (26u << 20));     // 16 MB
  __hip_bfloat16* W1t = (__hip_bfloat16*)(ws + (42u << 20));     // 512 KB
  __hip_bfloat16* W2t = (__hip_bfloat16*)(ws + (42u << 20) + (512u << 10)); // 4 MB
  __hip_bfloat16* W3t = (__hip_bfloat16*)(ws + (46u << 20) + (512u << 10)); // 512 KB

  {
    const size_t total = (size_t)BSZ * DD + 2u * 128 * 1024 + 2u * 1024 * 1024 + 2u * 1024 * 128;
    const int blocks = (int)((total + 255) / 256);
    prep_kernel<<<blocks, 256, 0, stream>>>(inputs, W1, W2, W3, xcur, inbuf, W1t, W2t, W3t);
  }

  const float dt = 1.0f / 32.0f;
  for (int bij = 0; bij < 2; ++bij) {
    const __hip_bfloat16* w1t_b = W1t + (size_t)bij * 128 * 1024;
    const __hip_bfloat16* w2t_b = W2t + (size_t)bij * 1024 * 1024;
    const __hip_bfloat16* w3t_b = W3t + (size_t)bij * 1024 * 128;
    const float* b1_b = b1 + (size_t)bij * 1024;
    const float* b2_b = b2 + (size_t)bij * 1024;
    const float* b3_b = b3 + (size_t)bij * 128;
    const float* tw = W1 + (size_t)bij * (129 * 1024) + 128 * 1024;  // time row

    for (int step = 0; step < 32; ++step) {
      for (int s = 0; s < 4; ++s) {
        const float t = step * dt + (s == 0 ? 0.f : (s == 3 ? dt : 0.5f * dt));
        l1_kernel<<<512, 256, 0, stream>>>(inbuf, w1t_b, b1_b, tw, t, H1b);
        l2_kernel<<<512, 256, 0, stream>>>(H1b, w2t_b, b2_b, H2b);
        const bool last = (bij == 1 && step == 31 && s == 3);
        l3_kernel<<<256, 256, 0, stream>>>(H2b, w3t_b, b3_b, dt, s,
                                           xcur, kacc, last ? out : xcur, inbuf);
      }
    }
  }
}